// Round 10
// baseline (160.103 us; speedup 1.0000x reference)
//
#include <hip/hip_runtime.h>
#include <hip/hip_bf16.h>

typedef unsigned short u16;
typedef unsigned int u32;
typedef __attribute__((ext_vector_type(8))) short short8;
typedef __attribute__((ext_vector_type(4))) short s16x4;
typedef __attribute__((ext_vector_type(4))) float f32x4;
typedef __attribute__((ext_vector_type(4))) u32 u32v4;

__device__ __forceinline__ u16 f2bf(float f) {
    u32 u = __float_as_uint(f);
    return (u16)((u + 0x7FFFu + ((u >> 16) & 1u)) >> 16);   // RNE
}
__device__ __forceinline__ u32 pack2bf(float a, float b) {
    __hip_bfloat162 h = __float22bfloat162_rn(float2{a, b});
    return *reinterpret_cast<u32*>(&h);
}
__device__ __forceinline__ float exp2hw(float x) {
    float r;
    asm("v_exp_f32 %0, %1" : "=v"(r) : "v"(x));
    return r;
}

__device__ __forceinline__ void gload16(const void* g, void* s) {
    __builtin_amdgcn_global_load_lds(
        (const __attribute__((address_space(1))) void*)g,
        (__attribute__((address_space(3))) void*)s, 16, 0, 0);
}

// ---------------- fused cast: 7 fp32 tensors -> bf16 ----------------
__global__ __launch_bounds__(256) void cast_all_kernel(
    const float* __restrict__ s0, const float* __restrict__ s1, const float* __restrict__ s2,
    const float* __restrict__ s3, const float* __restrict__ s4, const float* __restrict__ s5,
    const float* __restrict__ s6,
    u16* __restrict__ d0, u16* __restrict__ d1, u16* __restrict__ d2,
    u16* __restrict__ d3, u16* __restrict__ d4, u16* __restrict__ d5,
    u16* __restrict__ d6, int nBig, int nSmall)
{
    const int y = blockIdx.y;
    const float* s = y == 0 ? s0 : (y == 1 ? s1 : (y == 2 ? s2 : (y == 3 ? s3 : (y == 4 ? s4 : (y == 5 ? s5 : s6)))));
    u16* d = y == 0 ? d0 : (y == 1 ? d1 : (y == 2 ? d2 : (y == 3 ? d3 : (y == 4 ? d4 : (y == 5 ? d5 : d6)))));
    const int n = (y < 3) ? nBig : nSmall;
    int i = (blockIdx.x * 256 + threadIdx.x) * 4;
    const int stride = gridDim.x * 256 * 4;
    for (; i < n; i += stride) {
        float4 v = *(const float4*)(s + i);
        uint2 t;
        t.x = pack2bf(v.x, v.y);
        t.y = pack2bf(v.z, v.w);
        *(uint2*)(d + i) = t;
    }
}

// ---------------- GEMM template: 128x128 tile, 4 waves, dbuf, 1 barrier/iter ----
// Exactly the structure that measured 13us (o_gemm R3..R8).
// MODE 0: bf16 out, scaled (Q uses 0.125*log2e, K uses 1.0)
// MODE 1: bf16 out transposed per-batch Vt[b][d][s], s permuted within 32-blocks
//         (4-blk b -> ((b&3)<<1)|(b>>2)) to match attn's in-register P k-order.
// MODE 2: fp32 out + bias (O projection, writes d_out)
template<int MODE>
__global__ __launch_bounds__(256) void gemm_bt(
    const u16* __restrict__ A, const u16* __restrict__ W,
    const float* __restrict__ bias, void* __restrict__ outp, float scale)
{
    constexpr int N = 1024, K = 1024;
    __shared__ __align__(16) u16 Asm[2][4096];
    __shared__ __align__(16) u16 Bsm[2][4096];
    const int tid = threadIdx.x;
    const int wid = tid >> 6;
    const int lane = tid & 63;
    const int r15 = lane & 15, g = lane >> 4;
    const int fb = blockIdx.y * 8 + blockIdx.x;
    const int lsw = (fb & 7) * 32 + (fb >> 3);       // XCD-major swizzle
    const int m0 = (lsw >> 3) * 128, n0 = (lsw & 7) * 128;
    const int wr = wid >> 1, wc = wid & 1;

    f32x4 acc[4][4];
#pragma unroll
    for (int i = 0; i < 4; ++i)
#pragma unroll
        for (int j = 0; j < 4; ++j) acc[i][j] = (f32x4){0.f, 0.f, 0.f, 0.f};

    const int idx0 = tid, idx1 = tid + 256;
    const size_t aoff0 = (size_t)(m0 + (idx0 >> 2)) * K + (idx0 & 3) * 8;
    const size_t aoff1 = (size_t)(m0 + (idx1 >> 2)) * K + (idx1 & 3) * 8;
    const size_t boff0 = (size_t)(n0 + (idx0 >> 2)) * K + (idx0 & 3) * 8;
    const size_t boff1 = (size_t)(n0 + (idx1 >> 2)) * K + (idx1 & 3) * 8;
    const u16* abase = &Asm[0][0] + (wr * 64 + r15) * 32 + g * 8;
    const u16* bbase = &Bsm[0][0] + (wc * 64 + r15) * 32 + g * 8;

    gload16(A + aoff0, &Asm[0][wid * 512]);
    gload16(A + aoff1, &Asm[0][2048 + wid * 512]);
    gload16(W + boff0, &Bsm[0][wid * 512]);
    gload16(W + boff1, &Bsm[0][2048 + wid * 512]);
    __syncthreads();

#pragma unroll 2
    for (int t = 0; t < 32; ++t) {
        const int buf = t & 1;
        if (t < 31) {
            const int kt = (t + 1) * 32;
            gload16(A + aoff0 + kt, &Asm[buf ^ 1][wid * 512]);
            gload16(A + aoff1 + kt, &Asm[buf ^ 1][2048 + wid * 512]);
            gload16(W + boff0 + kt, &Bsm[buf ^ 1][wid * 512]);
            gload16(W + boff1 + kt, &Bsm[buf ^ 1][2048 + wid * 512]);
        }
        short8 af[4], bfr[4];
#pragma unroll
        for (int i = 0; i < 4; ++i) {
            af[i]  = *(const short8*)(abase + buf * 4096 + i * 512);
            bfr[i] = *(const short8*)(bbase + buf * 4096 + i * 512);
        }
#pragma unroll
        for (int i = 0; i < 4; ++i)
#pragma unroll
            for (int j = 0; j < 4; ++j)
                acc[i][j] = __builtin_amdgcn_mfma_f32_16x16x32_bf16(af[i], bfr[j], acc[i][j], 0, 0, 0);
        __syncthreads();
    }

#pragma unroll
    for (int i = 0; i < 4; ++i) {
        const int mbase = m0 + wr * 64 + i * 16 + g * 4;
#pragma unroll
        for (int j = 0; j < 4; ++j) {
            const int n = n0 + wc * 64 + j * 16 + r15;
            const float bb = bias[n];
            if constexpr (MODE == 0) {
                u16* ob = (u16*)outp;
#pragma unroll
                for (int r = 0; r < 4; ++r)
                    ob[(size_t)(mbase + r) * N + n] = f2bf((acc[i][j][r] + bb) * scale);
            } else if constexpr (MODE == 1) {
                u16* ob = (u16*)outp;
                const int b_ = mbase >> 11, s_ = mbase & 2047;
                const int blk = (s_ >> 2) & 7;
                const int pb = ((blk & 3) << 1) | (blk >> 2);
                const int s_new = (s_ & ~31) | (pb << 2);
                s16x4 pk;
#pragma unroll
                for (int r = 0; r < 4; ++r) pk[r] = (short)f2bf(acc[i][j][r] + bb);
                *(s16x4*)(ob + ((size_t)b_ << 21) + (size_t)n * 2048 + s_new) = pk;
            } else {
                float* of = (float*)outp;
#pragma unroll
                for (int r = 0; r < 4; ++r)
                    of[(size_t)(mbase + r) * N + n] = acc[i][j][r] + bb;
            }
        }
    }
}

// ---------------- flash attention v4 (unchanged, ~23us) ----------------
__global__ __launch_bounds__(256) void attn_kernel(
    const u16* __restrict__ Q, const u16* __restrict__ Kb,
    const u16* __restrict__ Vt, u16* __restrict__ Mo)
{
    __shared__ __align__(16) u16 Ksm[2][4096];
    __shared__ __align__(16) u16 Vsm[2][4096];
    const int tid = threadIdx.x;
    const int wid = tid >> 6, lane = tid & 63;
    const int r15 = lane & 15, g = lane >> 4;
    const int bid = blockIdx.x;
    const int l = (bid & 7) * 64 + (bid >> 3);
    const int bh = l >> 4;
    const int b = bh >> 4, h = bh & 15;
    const int q0 = (l & 15) * 128 + wid * 32;

    const u16* Qbase = Q + ((size_t)b * 2048 + q0) * 1024 + h * 64;
    short8 qf[2][2];
#pragma unroll
    for (int qt = 0; qt < 2; ++qt)
#pragma unroll
        for (int f = 0; f < 2; ++f)
            qf[qt][f] = *(const short8*)(Qbase + (size_t)(qt * 16 + r15) * 1024 + f * 32 + g * 8);

    const int p0 = tid, p1 = tid + 256;
    const int row0 = p0 >> 3, slot0s = (p0 & 7) ^ (row0 & 7);
    const int row1 = p1 >> 3, slot1s = (p1 & 7) ^ (row1 & 7);
    const u16* Ks0 = Kb + ((size_t)b * 2048 + row0) * 1024 + h * 64 + slot0s * 8;
    const u16* Ks1 = Kb + ((size_t)b * 2048 + row1) * 1024 + h * 64 + slot1s * 8;
    const u16* Vs0 = Vt + ((size_t)b << 21) + (size_t)(h * 64 + row0) * 2048 + slot0s * 8;
    const u16* Vs1 = Vt + ((size_t)b << 21) + (size_t)(h * 64 + row1) * 2048 + slot1s * 8;

    const int sA = r15 & 7;
    const int sl0 = (g ^ sA) * 8;
    const int sl1 = sl0 ^ 32;
    const u16* kb0 = &Ksm[0][0] + r15 * 64 + sl0;
    const u16* kb1 = &Ksm[0][0] + r15 * 64 + sl1;
    const u16* vb0 = &Vsm[0][0] + r15 * 64 + sl0;
    const u16* vb1 = &Vsm[0][0] + r15 * 64 + sl1;

    f32x4 acc[2][4];
#pragma unroll
    for (int qt = 0; qt < 2; ++qt)
#pragma unroll
        for (int d4 = 0; d4 < 4; ++d4) acc[qt][d4] = (f32x4){0.f, 0.f, 0.f, 0.f};
    f32x4 accl[2] = {(f32x4){0.f, 0.f, 0.f, 0.f}, (f32x4){0.f, 0.f, 0.f, 0.f}};
    const short8 vone = {0x3F80, 0x3F80, 0x3F80, 0x3F80, 0x3F80, 0x3F80, 0x3F80, 0x3F80};

    gload16(Ks0, &Ksm[0][wid * 512]);
    gload16(Ks1, &Ksm[0][2048 + wid * 512]);
    gload16(Vs0, &Vsm[0][wid * 512]);
    gload16(Vs1, &Vsm[0][2048 + wid * 512]);
    Ks0 += 65536; Ks1 += 65536; Vs0 += 64; Vs1 += 64;
    __syncthreads();

#pragma unroll 2
    for (int t = 0; t < 32; ++t) {
        const int buf = t & 1;
        if (t < 31) {
            gload16(Ks0, &Ksm[buf ^ 1][wid * 512]);
            gload16(Ks1, &Ksm[buf ^ 1][2048 + wid * 512]);
            gload16(Vs0, &Vsm[buf ^ 1][wid * 512]);
            gload16(Vs1, &Vsm[buf ^ 1][2048 + wid * 512]);
            Ks0 += 65536; Ks1 += 65536; Vs0 += 64; Vs1 += 64;
        }

        short8 kf[4][2];
#pragma unroll
        for (int kt = 0; kt < 4; ++kt) {
            kf[kt][0] = *(const short8*)(kb0 + buf * 4096 + kt * 1024);
            kf[kt][1] = *(const short8*)(kb1 + buf * 4096 + kt * 1024);
        }

        f32x4 st[2][4];
#pragma unroll
        for (int qt = 0; qt < 2; ++qt)
#pragma unroll
            for (int kt = 0; kt < 4; ++kt) {
                f32x4 zz = (f32x4){0.f, 0.f, 0.f, 0.f};
                zz = __builtin_amdgcn_mfma_f32_16x16x32_bf16(kf[kt][0], qf[qt][0], zz, 0, 0, 0);
                zz = __builtin_amdgcn_mfma_f32_16x16x32_bf16(kf[kt][1], qf[qt][1], zz, 0, 0, 0);
                st[qt][kt] = zz;
            }

        u32v4 pA[2], pB[2];
#pragma unroll
        for (int qt = 0; qt < 2; ++qt) {
#pragma unroll
            for (int kt = 0; kt < 4; ++kt) {
                float e0 = exp2hw(st[qt][kt][0]);
                float e1 = exp2hw(st[qt][kt][1]);
                float e2 = exp2hw(st[qt][kt][2]);
                float e3 = exp2hw(st[qt][kt][3]);
                u32 lo = pack2bf(e0, e1);
                u32 hi = pack2bf(e2, e3);
                if (kt < 2) { pA[qt][kt * 2] = lo; pA[qt][kt * 2 + 1] = hi; }
                else        { pB[qt][(kt - 2) * 2] = lo; pB[qt][(kt - 2) * 2 + 1] = hi; }
            }
        }

        accl[0] = __builtin_amdgcn_mfma_f32_16x16x32_bf16(vone, __builtin_bit_cast(short8, pA[0]), accl[0], 0, 0, 0);
        accl[0] = __builtin_amdgcn_mfma_f32_16x16x32_bf16(vone, __builtin_bit_cast(short8, pB[0]), accl[0], 0, 0, 0);
        accl[1] = __builtin_amdgcn_mfma_f32_16x16x32_bf16(vone, __builtin_bit_cast(short8, pA[1]), accl[1], 0, 0, 0);
        accl[1] = __builtin_amdgcn_mfma_f32_16x16x32_bf16(vone, __builtin_bit_cast(short8, pB[1]), accl[1], 0, 0, 0);

#pragma unroll
        for (int d4 = 0; d4 < 4; ++d4) {
            short8 vf0 = *(const short8*)(vb0 + buf * 4096 + d4 * 1024);
            short8 vf1 = *(const short8*)(vb1 + buf * 4096 + d4 * 1024);
            acc[0][d4] = __builtin_amdgcn_mfma_f32_16x16x32_bf16(vf0, __builtin_bit_cast(short8, pA[0]), acc[0][d4], 0, 0, 0);
            acc[0][d4] = __builtin_amdgcn_mfma_f32_16x16x32_bf16(vf1, __builtin_bit_cast(short8, pB[0]), acc[0][d4], 0, 0, 0);
            acc[1][d4] = __builtin_amdgcn_mfma_f32_16x16x32_bf16(vf0, __builtin_bit_cast(short8, pA[1]), acc[1][d4], 0, 0, 0);
            acc[1][d4] = __builtin_amdgcn_mfma_f32_16x16x32_bf16(vf1, __builtin_bit_cast(short8, pB[1]), acc[1][d4], 0, 0, 0);
        }
        __syncthreads();
    }

#pragma unroll
    for (int qt = 0; qt < 2; ++qt) {
        const float inv = 1.f / accl[qt][0];
        const size_t orow = ((size_t)b * 2048 + q0 + qt * 16 + r15) * 1024 + h * 64;
#pragma unroll
        for (int d4 = 0; d4 < 4; ++d4) {
            uint2 o;
            o.x = pack2bf(acc[qt][d4][0] * inv, acc[qt][d4][1] * inv);
            o.y = pack2bf(acc[qt][d4][2] * inv, acc[qt][d4][3] * inv);
            *(uint2*)(Mo + orow + d4 * 16 + g * 4) = o;
        }
    }
}

extern "C" void kernel_launch(void* const* d_in, const int* in_sizes, int n_in,
                              void* d_out, int out_size, void* d_ws, size_t ws_size,
                              hipStream_t stream) {
    (void)in_sizes; (void)n_in; (void)out_size; (void)ws_size;
    const float* query = (const float*)d_in[0];
    const float* key   = (const float*)d_in[1];
    const float* value = (const float*)d_in[2];
    const float* q_w = (const float*)d_in[3];
    const float* q_b = (const float*)d_in[4];
    const float* k_w = (const float*)d_in[5];
    const float* k_b = (const float*)d_in[6];
    const float* v_w = (const float*)d_in[7];
    const float* v_b = (const float*)d_in[8];
    const float* o_w = (const float*)d_in[9];
    const float* o_b = (const float*)d_in[10];

    const size_t NE = (size_t)4096 * 1024;
    const size_t MW = (size_t)1024 * 1024;
    u16* w = (u16*)d_ws;
    u16* Xq = w;
    u16* Xk = Xq + NE;
    u16* Xv = Xk + NE;
    u16* Wq = Xv + NE;
    u16* Wk = Wq + MW;
    u16* Wv = Wk + MW;
    u16* Wo = Wv + MW;
    u16* Qb = Wo + MW;
    u16* Kb = Qb + NE;
    u16* Vt = Kb + NE;      // [B][1024 d][2048 s], s permuted within 32-blocks
    u16* Mo = Vt + NE;

    cast_all_kernel<<<dim3(2048, 7), 256, 0, stream>>>(
        query, key, value, q_w, k_w, v_w, o_w,
        Xq, Xk, Xv, Wq, Wk, Wv, Wo, (int)NE, (int)MW);
    gemm_bt<0><<<dim3(8, 32), 256, 0, stream>>>(Xq, Wq, q_b, Qb, 0.125f * 1.4426950408889634f);
    gemm_bt<0><<<dim3(8, 32), 256, 0, stream>>>(Xk, Wk, k_b, Kb, 1.0f);
    gemm_bt<1><<<dim3(8, 32), 256, 0, stream>>>(Xv, Wv, v_b, Vt, 1.0f);
    attn_kernel<<<dim3(512), 256, 0, stream>>>(Qb, Kb, Vt, Mo);
    gemm_bt<2><<<dim3(8, 32), 256, 0, stream>>>(Mo, Wo, o_b, d_out, 1.0f);
}

// Round 11
// 133.818 us; speedup vs baseline: 1.1964x; 1.1964x over previous
//
#include <hip/hip_runtime.h>
#include <hip/hip_bf16.h>

typedef unsigned short u16;
typedef unsigned int u32;
typedef __attribute__((ext_vector_type(8))) short short8;
typedef __attribute__((ext_vector_type(4))) short s16x4;
typedef __attribute__((ext_vector_type(4))) float f32x4;
typedef __attribute__((ext_vector_type(4))) u32 u32v4;

__device__ __forceinline__ u16 f2bf(float f) {
    u32 u = __float_as_uint(f);
    return (u16)((u + 0x7FFFu + ((u >> 16) & 1u)) >> 16);   // RNE
}
__device__ __forceinline__ u32 pack2bf(float a, float b) {
    __hip_bfloat162 h = __float22bfloat162_rn(float2{a, b});
    return *reinterpret_cast<u32*>(&h);
}
__device__ __forceinline__ float exp2hw(float x) {
    float r;
    asm("v_exp_f32 %0, %1" : "=v"(r) : "v"(x));
    return r;
}

__device__ __forceinline__ void gload16(const void* g, void* s) {
    __builtin_amdgcn_global_load_lds(
        (const __attribute__((address_space(1))) void*)g,
        (__attribute__((address_space(3))) void*)s, 16, 0, 0);
}

// ---------------- fused cast: 7 fp32 tensors -> bf16 ----------------
__global__ __launch_bounds__(256) void cast_all_kernel(
    const float* __restrict__ s0, const float* __restrict__ s1, const float* __restrict__ s2,
    const float* __restrict__ s3, const float* __restrict__ s4, const float* __restrict__ s5,
    const float* __restrict__ s6,
    u16* __restrict__ d0, u16* __restrict__ d1, u16* __restrict__ d2,
    u16* __restrict__ d3, u16* __restrict__ d4, u16* __restrict__ d5,
    u16* __restrict__ d6, int nBig, int nSmall)
{
    const int y = blockIdx.y;
    const float* s = y == 0 ? s0 : (y == 1 ? s1 : (y == 2 ? s2 : (y == 3 ? s3 : (y == 4 ? s4 : (y == 5 ? s5 : s6)))));
    u16* d = y == 0 ? d0 : (y == 1 ? d1 : (y == 2 ? d2 : (y == 3 ? d3 : (y == 4 ? d4 : (y == 5 ? d5 : d6)))));
    const int n = (y < 3) ? nBig : nSmall;
    int i = (blockIdx.x * 256 + threadIdx.x) * 4;
    const int stride = gridDim.x * 256 * 4;
    for (; i < n; i += stride) {
        float4 v = *(const float4*)(s + i);
        uint2 t;
        t.x = pack2bf(v.x, v.y);
        t.y = pack2bf(v.z, v.w);
        *(uint2*)(d + i) = t;
    }
}

// ---------------- fused QKV GEMM: EXACT R3 form (3D grid, dbuf, 1 barrier/iter) ----
// z=blockIdx.z selects Q/K/V. Q: bf16 out scaled by 0.125*log2e. K: bf16.
// V: bf16 transposed per-batch Vt[b][d][s], s permuted within 32-blocks
// (4-blk b -> ((b&3)<<1)|(b>>2)) to match attn's in-register P k-order.
__global__ __launch_bounds__(256) void qkv_gemm(
    const u16* __restrict__ Xq, const u16* __restrict__ Xk, const u16* __restrict__ Xv,
    const u16* __restrict__ Wq, const u16* __restrict__ Wk, const u16* __restrict__ Wv,
    const float* __restrict__ qb, const float* __restrict__ kb, const float* __restrict__ vb,
    u16* __restrict__ Qo, u16* __restrict__ Ko, u16* __restrict__ Vo)
{
    constexpr int N = 1024, K = 1024;
    __shared__ __align__(16) u16 Asm[2][4096];
    __shared__ __align__(16) u16 Bsm[2][4096];
    const int z = blockIdx.z;
    const u16* A = z == 0 ? Xq : (z == 1 ? Xk : Xv);
    const u16* W = z == 0 ? Wq : (z == 1 ? Wk : Wv);
    const float* bias = z == 0 ? qb : (z == 1 ? kb : vb);

    const int tid = threadIdx.x;
    const int wid = tid >> 6;
    const int lane = tid & 63;
    const int r15 = lane & 15, g = lane >> 4;
    const int fb = blockIdx.y * 8 + blockIdx.x;
    const int lsw = (fb & 7) * 32 + (fb >> 3);
    const int m0 = (lsw >> 3) * 128, n0 = (lsw & 7) * 128;
    const int wr = wid >> 1, wc = wid & 1;

    f32x4 acc[4][4];
#pragma unroll
    for (int i = 0; i < 4; ++i)
#pragma unroll
        for (int j = 0; j < 4; ++j) acc[i][j] = (f32x4){0.f, 0.f, 0.f, 0.f};

    const int idx0 = tid, idx1 = tid + 256;
    const size_t aoff0 = (size_t)(m0 + (idx0 >> 2)) * K + (idx0 & 3) * 8;
    const size_t aoff1 = (size_t)(m0 + (idx1 >> 2)) * K + (idx1 & 3) * 8;
    const size_t boff0 = (size_t)(n0 + (idx0 >> 2)) * K + (idx0 & 3) * 8;
    const size_t boff1 = (size_t)(n0 + (idx1 >> 2)) * K + (idx1 & 3) * 8;

    auto STAGE = [&](int buf, int kt) {
        gload16(A + aoff0 + kt, &Asm[buf][wid * 512]);
        gload16(A + aoff1 + kt, &Asm[buf][2048 + wid * 512]);
        gload16(W + boff0 + kt, &Bsm[buf][wid * 512]);
        gload16(W + boff1 + kt, &Bsm[buf][2048 + wid * 512]);
    };

    STAGE(0, 0);
    __syncthreads();
    for (int t = 0; t < 32; ++t) {
        const int buf = t & 1;
        if (t < 31) STAGE(buf ^ 1, (t + 1) * 32);
        short8 af[4], bfr[4];
#pragma unroll
        for (int i = 0; i < 4; ++i) {
            af[i]  = *(const short8*)(&Asm[buf][0] + (wr * 64 + i * 16 + r15) * 32 + g * 8);
            bfr[i] = *(const short8*)(&Bsm[buf][0] + (wc * 64 + i * 16 + r15) * 32 + g * 8);
        }
#pragma unroll
        for (int i = 0; i < 4; ++i)
#pragma unroll
            for (int j = 0; j < 4; ++j)
                acc[i][j] = __builtin_amdgcn_mfma_f32_16x16x32_bf16(af[i], bfr[j], acc[i][j], 0, 0, 0);
        __syncthreads();
    }

    const float scale = (z == 0) ? 0.125f * 1.4426950408889634f : 1.0f;
    u16* ob = z == 0 ? Qo : (z == 1 ? Ko : Vo);
#pragma unroll
    for (int i = 0; i < 4; ++i) {
        const int mbase = m0 + wr * 64 + i * 16 + g * 4;
#pragma unroll
        for (int j = 0; j < 4; ++j) {
            const int n = n0 + wc * 64 + j * 16 + r15;
            const float bb = bias[n];
            if (z < 2) {
#pragma unroll
                for (int r = 0; r < 4; ++r)
                    ob[(size_t)(mbase + r) * N + n] = f2bf((acc[i][j][r] + bb) * scale);
            } else {
                const int b_ = mbase >> 11, s_ = mbase & 2047;
                const int blk = (s_ >> 2) & 7;
                const int pb = ((blk & 3) << 1) | (blk >> 2);
                const int s_new = (s_ & ~31) | (pb << 2);
                s16x4 pk;
#pragma unroll
                for (int r = 0; r < 4; ++r) pk[r] = (short)f2bf(acc[i][j][r] + bb);
                *(s16x4*)(ob + ((size_t)b_ << 21) + (size_t)n * 2048 + s_new) = pk;
            }
        }
    }
}

// ---------------- O projection GEMM: fp32 out, dbuf (R3 form) ----------------
__global__ __launch_bounds__(256) void o_gemm(
    const u16* __restrict__ A, const u16* __restrict__ W,
    const float* __restrict__ bias, float* __restrict__ outp)
{
    constexpr int N = 1024, K = 1024;
    __shared__ __align__(16) u16 Asm[2][4096];
    __shared__ __align__(16) u16 Bsm[2][4096];
    const int tid = threadIdx.x;
    const int wid = tid >> 6;
    const int lane = tid & 63;
    const int r15 = lane & 15, g = lane >> 4;
    const int fb = blockIdx.y * 8 + blockIdx.x;
    const int lsw = (fb & 7) * 32 + (fb >> 3);
    const int m0 = (lsw >> 3) * 128, n0 = (lsw & 7) * 128;
    const int wr = wid >> 1, wc = wid & 1;

    f32x4 acc[4][4];
#pragma unroll
    for (int i = 0; i < 4; ++i)
#pragma unroll
        for (int j = 0; j < 4; ++j) acc[i][j] = (f32x4){0.f, 0.f, 0.f, 0.f};

    const int idx0 = tid, idx1 = tid + 256;
    const size_t aoff0 = (size_t)(m0 + (idx0 >> 2)) * K + (idx0 & 3) * 8;
    const size_t aoff1 = (size_t)(m0 + (idx1 >> 2)) * K + (idx1 & 3) * 8;
    const size_t boff0 = (size_t)(n0 + (idx0 >> 2)) * K + (idx0 & 3) * 8;
    const size_t boff1 = (size_t)(n0 + (idx1 >> 2)) * K + (idx1 & 3) * 8;

    auto STAGE = [&](int buf, int kt) {
        gload16(A + aoff0 + kt, &Asm[buf][wid * 512]);
        gload16(A + aoff1 + kt, &Asm[buf][2048 + wid * 512]);
        gload16(W + boff0 + kt, &Bsm[buf][wid * 512]);
        gload16(W + boff1 + kt, &Bsm[buf][2048 + wid * 512]);
    };

    STAGE(0, 0);
    __syncthreads();
    for (int t = 0; t < 32; ++t) {
        const int buf = t & 1;
        if (t < 31) STAGE(buf ^ 1, (t + 1) * 32);
        short8 af[4], bfr[4];
#pragma unroll
        for (int i = 0; i < 4; ++i) {
            af[i]  = *(const short8*)(&Asm[buf][0] + (wr * 64 + i * 16 + r15) * 32 + g * 8);
            bfr[i] = *(const short8*)(&Bsm[buf][0] + (wc * 64 + i * 16 + r15) * 32 + g * 8);
        }
#pragma unroll
        for (int i = 0; i < 4; ++i)
#pragma unroll
            for (int j = 0; j < 4; ++j)
                acc[i][j] = __builtin_amdgcn_mfma_f32_16x16x32_bf16(af[i], bfr[j], acc[i][j], 0, 0, 0);
        __syncthreads();
    }

#pragma unroll
    for (int i = 0; i < 4; ++i) {
        const int mbase = m0 + wr * 64 + i * 16 + g * 4;
#pragma unroll
        for (int j = 0; j < 4; ++j) {
            const int n = n0 + wc * 64 + j * 16 + r15;
            const float bb = bias[n];
#pragma unroll
            for (int r = 0; r < 4; ++r)
                outp[(size_t)(mbase + r) * N + n] = acc[i][j][r] + bb;
        }
    }
}

// ---------------- flash attention v5: 16 q/wave, 1024 blocks (4/CU) ----------------
// 4 waves/block, 64 q-rows/block. KVBLK=64, dbuf LDS. P in registers (permuted
// k-order matched by Vt layout). exp2-domain, ones-MFMA lsum. TLP doubled vs v4.
__global__ __launch_bounds__(256) void attn_kernel(
    const u16* __restrict__ Q, const u16* __restrict__ Kb,
    const u16* __restrict__ Vt, u16* __restrict__ Mo)
{
    __shared__ __align__(16) u16 Ksm[2][4096];
    __shared__ __align__(16) u16 Vsm[2][4096];
    const int tid = threadIdx.x;
    const int wid = tid >> 6, lane = tid & 63;
    const int r15 = lane & 15, g = lane >> 4;
    // XCD swizzle: 1024 blocks, each XCD serves 4 consecutive (b,h) (2MB K+V in L2)
    const int bid = blockIdx.x;
    const int l = (bid & 7) * 128 + (bid >> 3);
    const int bh = l >> 5;
    const int b = bh >> 4, h = bh & 15;
    const int q0 = (l & 31) * 64 + wid * 16;

    // persistent Q fragment: q = q0 + r15, d = f*32 + g*8
    const u16* Qrow = Q + ((size_t)b * 2048 + q0 + r15) * 1024 + h * 64;
    short8 qf[2];
    qf[0] = *(const short8*)(Qrow + g * 8);
    qf[1] = *(const short8*)(Qrow + 32 + g * 8);

    // staging (pre-swizzled sources), advanced per tile
    const int p0 = tid, p1 = tid + 256;
    const int row0 = p0 >> 3, slot0s = (p0 & 7) ^ (row0 & 7);
    const int row1 = p1 >> 3, slot1s = (p1 & 7) ^ (row1 & 7);
    const u16* Ks0 = Kb + ((size_t)b * 2048 + row0) * 1024 + h * 64 + slot0s * 8;
    const u16* Ks1 = Kb + ((size_t)b * 2048 + row1) * 1024 + h * 64 + slot1s * 8;
    const u16* Vs0 = Vt + ((size_t)b << 21) + (size_t)(h * 64 + row0) * 2048 + slot0s * 8;
    const u16* Vs1 = Vt + ((size_t)b << 21) + (size_t)(h * 64 + row1) * 2048 + slot1s * 8;

    const int sA = r15 & 7;
    const int sl0 = (g ^ sA) * 8;
    const int sl1 = sl0 ^ 32;
    const u16* kb0 = &Ksm[0][0] + r15 * 64 + sl0;
    const u16* kb1 = &Ksm[0][0] + r15 * 64 + sl1;
    const u16* vb0 = &Vsm[0][0] + r15 * 64 + sl0;
    const u16* vb1 = &Vsm[0][0] + r15 * 64 + sl1;

    f32x4 acc[4];
#pragma unroll
    for (int d4 = 0; d4 < 4; ++d4) acc[d4] = (f32x4){0.f, 0.f, 0.f, 0.f};
    f32x4 accl = (f32x4){0.f, 0.f, 0.f, 0.f};
    const short8 vone = {0x3F80, 0x3F80, 0x3F80, 0x3F80, 0x3F80, 0x3F80, 0x3F80, 0x3F80};

    gload16(Ks0, &Ksm[0][wid * 512]);
    gload16(Ks1, &Ksm[0][2048 + wid * 512]);
    gload16(Vs0, &Vsm[0][wid * 512]);
    gload16(Vs1, &Vsm[0][2048 + wid * 512]);
    Ks0 += 65536; Ks1 += 65536; Vs0 += 64; Vs1 += 64;
    __syncthreads();

#pragma unroll 2
    for (int t = 0; t < 32; ++t) {
        const int buf = t & 1;
        if (t < 31) {
            gload16(Ks0, &Ksm[buf ^ 1][wid * 512]);
            gload16(Ks1, &Ksm[buf ^ 1][2048 + wid * 512]);
            gload16(Vs0, &Vsm[buf ^ 1][wid * 512]);
            gload16(Vs1, &Vsm[buf ^ 1][2048 + wid * 512]);
            Ks0 += 65536; Ks1 += 65536; Vs0 += 64; Vs1 += 64;
        }

        short8 kf[4][2];
#pragma unroll
        for (int kt = 0; kt < 4; ++kt) {
            kf[kt][0] = *(const short8*)(kb0 + buf * 4096 + kt * 1024);
            kf[kt][1] = *(const short8*)(kb1 + buf * 4096 + kt * 1024);
        }

        f32x4 st[4];
#pragma unroll
        for (int kt = 0; kt < 4; ++kt) {
            f32x4 zz = (f32x4){0.f, 0.f, 0.f, 0.f};
            zz = __builtin_amdgcn_mfma_f32_16x16x32_bf16(kf[kt][0], qf[0], zz, 0, 0, 0);
            zz = __builtin_amdgcn_mfma_f32_16x16x32_bf16(kf[kt][1], qf[1], zz, 0, 0, 0);
            st[kt] = zz;
        }

        u32v4 pA, pB;
#pragma unroll
        for (int kt = 0; kt < 4; ++kt) {
            float e0 = exp2hw(st[kt][0]);
            float e1 = exp2hw(st[kt][1]);
            float e2 = exp2hw(st[kt][2]);
            float e3 = exp2hw(st[kt][3]);
            u32 lo = pack2bf(e0, e1);
            u32 hi = pack2bf(e2, e3);
            if (kt < 2) { pA[kt * 2] = lo; pA[kt * 2 + 1] = hi; }
            else        { pB[(kt - 2) * 2] = lo; pB[(kt - 2) * 2 + 1] = hi; }
        }

        accl = __builtin_amdgcn_mfma_f32_16x16x32_bf16(vone, __builtin_bit_cast(short8, pA), accl, 0, 0, 0);
        accl = __builtin_amdgcn_mfma_f32_16x16x32_bf16(vone, __builtin_bit_cast(short8, pB), accl, 0, 0, 0);

#pragma unroll
        for (int d4 = 0; d4 < 4; ++d4) {
            short8 vf0 = *(const short8*)(vb0 + buf * 4096 + d4 * 1024);
            short8 vf1 = *(const short8*)(vb1 + buf * 4096 + d4 * 1024);
            acc[d4] = __builtin_amdgcn_mfma_f32_16x16x32_bf16(vf0, __builtin_bit_cast(short8, pA), acc[d4], 0, 0, 0);
            acc[d4] = __builtin_amdgcn_mfma_f32_16x16x32_bf16(vf1, __builtin_bit_cast(short8, pB), acc[d4], 0, 0, 0);
        }
        __syncthreads();
    }

    const float inv = 1.f / accl[0];
    const size_t orow = ((size_t)b * 2048 + q0 + r15) * 1024 + h * 64;
#pragma unroll
    for (int d4 = 0; d4 < 4; ++d4) {
        uint2 o;
        o.x = pack2bf(acc[d4][0] * inv, acc[d4][1] * inv);
        o.y = pack2bf(acc[d4][2] * inv, acc[d4][3] * inv);
        *(uint2*)(Mo + orow + d4 * 16 + g * 4) = o;
    }
}

extern "C" void kernel_launch(void* const* d_in, const int* in_sizes, int n_in,
                              void* d_out, int out_size, void* d_ws, size_t ws_size,
                              hipStream_t stream) {
    (void)in_sizes; (void)n_in; (void)out_size; (void)ws_size;
    const float* query = (const float*)d_in[0];
    const float* key   = (const float*)d_in[1];
    const float* value = (const float*)d_in[2];
    const float* q_w = (const float*)d_in[3];
    const float* q_b = (const float*)d_in[4];
    const float* k_w = (const float*)d_in[5];
    const float* k_b = (const float*)d_in[6];
    const float* v_w = (const float*)d_in[7];
    const float* v_b = (const float*)d_in[8];
    const float* o_w = (const float*)d_in[9];
    const float* o_b = (const float*)d_in[10];

    const size_t NE = (size_t)4096 * 1024;
    const size_t MW = (size_t)1024 * 1024;
    u16* w = (u16*)d_ws;
    u16* Xq = w;
    u16* Xk = Xq + NE;
    u16* Xv = Xk + NE;
    u16* Wq = Xv + NE;
    u16* Wk = Wq + MW;
    u16* Wv = Wk + MW;
    u16* Wo = Wv + MW;
    u16* Qb = Wo + MW;
    u16* Kb = Qb + NE;
    u16* Vt = Kb + NE;      // [B][1024 d][2048 s], s permuted within 32-blocks
    u16* Mo = Vt + NE;

    cast_all_kernel<<<dim3(2048, 7), 256, 0, stream>>>(
        query, key, value, q_w, k_w, v_w, o_w,
        Xq, Xk, Xv, Wq, Wk, Wv, Wo, (int)NE, (int)MW);
    qkv_gemm<<<dim3(8, 32, 3), 256, 0, stream>>>(
        Xq, Xk, Xv, Wq, Wk, Wv, q_b, k_b, v_b, Qb, Kb, Vt);
    attn_kernel<<<dim3(1024), 256, 0, stream>>>(Qb, Kb, Vt, Mo);
    o_gemm<<<dim3(8, 32), 256, 0, stream>>>(Mo, Wo, o_b, (float*)d_out);
}